// Round 8
// baseline (241.148 us; speedup 1.0000x reference)
//
#include <hip/hip_runtime.h>
#include <math.h>

#define T_IN 2048
#define TP   2051   // T+3 conv output length
#define F    256
#define H    384
#define NTB  129    // 16-t tiles in KB
#define NC3  257    // 8-t chunks in KC
#define NCS  258    // cs rows (2 per KB t-tile)

__device__ __forceinline__ float logsig(float z) {
    return (z >= 0.0f) ? -log1pf(__expf(-z)) : z - log1pf(__expf(z));
}

// ================= KB: grid (129,7) x 64 threads =================
// by<6 : GEMM tile 16t x 64b x {Wk,Wi,Wf}. Lane owns column b=by*64+tid.
//        Phase0: conv 16 xp rows -> global scratch slice (idempotent across by).
//        Main:   W chunk (32k x 3) in registers; a = wave-uniform broadcast loads;
//        inner loop is register-only FMA (no LDS, no barriers).
// by==6: bx<6 -> q/o projections at t=2050; bx==6 -> zero zf/Gf/ticket.
__global__ __launch_bounds__(64) void KB(
    const float* __restrict__ x, const float* __restrict__ cw, const float* __restrict__ cb,
    const float* __restrict__ Wk, const float* __restrict__ bk,
    const float* __restrict__ Wi, const float* __restrict__ bi,
    const float* __restrict__ Wf, const float* __restrict__ bf,
    const float* __restrict__ Wq, const float* __restrict__ bq,
    const float* __restrict__ Wo, const float* __restrict__ bo,
    float* __restrict__ xpc, float* __restrict__ zk, float* __restrict__ ai,
    float* __restrict__ lf, float* __restrict__ cs,
    float* __restrict__ qv, float* __restrict__ ov, float* __restrict__ zf) {
    int tid = threadIdx.x;
    int bx = blockIdx.x, by = blockIdx.y;

    if (by == 6) {
        if (bx == 6) {
            for (int i = tid; i < 264; i += 64) zf[i] = 0.0f;   // z[256], G, ticket
            return;
        }
        if (bx > 6) return;
        // q/o for rows bx*64 .. bx*64+63; xp[2050] = cb + cw0*x[2047] (taps 1..3 OOB)
        int lane = tid;
        float w0 = cw[0], bb = cb[0];
        float4 xr = *(const float4*)&x[2047 * 256 + lane * 4];
        float4 xv = {bb + w0 * xr.x, bb + w0 * xr.y, bb + w0 * xr.z, bb + w0 * xr.w};
        for (int r = 0; r < 64; ++r) {
            int row = bx * 64 + r;
            float4 q4 = *(const float4*)&Wq[row * 256 + lane * 4];
            float4 o4 = *(const float4*)&Wo[row * 256 + lane * 4];
            float aq = fmaf(xv.x, q4.x, fmaf(xv.y, q4.y, fmaf(xv.z, q4.z, xv.w * q4.w)));
            float ao = fmaf(xv.x, o4.x, fmaf(xv.y, o4.y, fmaf(xv.z, o4.z, xv.w * o4.w)));
            #pragma unroll
            for (int off = 32; off; off >>= 1) {
                aq += __shfl_down(aq, off, 64);
                ao += __shfl_down(ao, off, 64);
            }
            if (lane == 0) {
                qv[row] = aq + bq[row];
                ov[row] = 1.0f / (1.0f + __expf(-(ao + bo[row])));
            }
        }
        return;
    }

    int t0 = bx * 16;
    int b  = by * 64 + tid;
    float* xs = xpc + bx * 4096;       // this t-tile's scratch (16 x 256)

    // ---- phase0: conv 16 rows -> xs (4 threads/row, 64B-contiguous lane groups)
    {
        float w4[4] = {cw[0], cw[1], cw[2], cw[3]};
        float bb = cb[0];
        int r = tid >> 2;
        int cb0 = (tid & 3) * 4;
        int t = t0 + r;
        for (int c16 = 0; c16 < 16; ++c16) {
            int c = cb0 + c16 * 16;
            float4 acc = {0.f, 0.f, 0.f, 0.f};
            if (t < TP) {
                acc.x = bb; acc.y = bb; acc.z = bb; acc.w = bb;
                #pragma unroll
                for (int j = 0; j < 4; ++j) {
                    int tt = t - 3 + j;
                    if (tt >= 0 && tt < T_IN) {
                        float4 xv = *(const float4*)&x[tt * 256 + c];
                        float wj = w4[j];
                        acc.x = fmaf(wj, xv.x, acc.x);
                        acc.y = fmaf(wj, xv.y, acc.y);
                        acc.z = fmaf(wj, xv.z, acc.z);
                        acc.w = fmaf(wj, xv.w, acc.w);
                    }
                }
            }
            *(float4*)&xs[r * 256 + c] = acc;
        }
    }
    // single wave: drain stores, then safe to read own slice (L1/L2 of this CU)
    asm volatile("s_waitcnt vmcnt(0)" ::: "memory");

    // ---- main: register-only FMA loop
    float acc0[16], acc1[16], acc2[16];
    #pragma unroll
    for (int t = 0; t < 16; ++t) { acc0[t] = 0.f; acc1[t] = 0.f; acc2[t] = 0.f; }
    const float* pWk = Wk + b * 256;
    const float* pWi = Wi + b * 256;
    const float* pWf = Wf + b * 256;
    for (int kc = 0; kc < 8; ++kc) {
        int k0 = kc * 32;
        float4 Bk[8], Bi[8], Bf[8];
        #pragma unroll
        for (int q = 0; q < 8; ++q) {
            Bk[q] = *(const float4*)&pWk[k0 + q * 4];
            Bi[q] = *(const float4*)&pWi[k0 + q * 4];
            Bf[q] = *(const float4*)&pWf[k0 + q * 4];
        }
        #pragma unroll
        for (int t = 0; t < 16; ++t) {
            const float4* ap = (const float4*)&xs[t * 256 + k0];   // wave-uniform
            #pragma unroll
            for (int q = 0; q < 8; ++q) {
                float4 a = ap[q];
                acc0[t] = fmaf(a.x, Bk[q].x, acc0[t]);
                acc1[t] = fmaf(a.x, Bi[q].x, acc1[t]);
                acc2[t] = fmaf(a.x, Bf[q].x, acc2[t]);
                acc0[t] = fmaf(a.y, Bk[q].y, acc0[t]);
                acc1[t] = fmaf(a.y, Bi[q].y, acc1[t]);
                acc2[t] = fmaf(a.y, Bf[q].y, acc2[t]);
                acc0[t] = fmaf(a.z, Bk[q].z, acc0[t]);
                acc1[t] = fmaf(a.z, Bi[q].z, acc1[t]);
                acc2[t] = fmaf(a.z, Bf[q].z, acc2[t]);
                acc0[t] = fmaf(a.w, Bk[q].w, acc0[t]);
                acc1[t] = fmaf(a.w, Bi[q].w, acc1[t]);
                acc2[t] = fmaf(a.w, Bf[q].w, acc2[t]);
            }
        }
    }
    // ---- epilogue: bias + activations + coalesced column stores + cs sums
    float bkv = bk[b], biv = bi[b], bfv = bf[b];
    const float sc = 0.05103103630798287f;  // 1/sqrt(384)
    float lsA = 0.f, lsB = 0.f;
    #pragma unroll
    for (int t = 0; t < 16; ++t) {
        int tt = t0 + t;
        if (tt < TP) {
            int row = tt * H + b;
            zk[row] = (acc0[t] + bkv) * sc;
            ai[row] = acc1[t] + biv;
            float l = logsig(acc2[t] + bfv);
            lf[row] = l;
            if (t < 8) lsA += l; else lsB += l;
        }
    }
    cs[(2 * bx + 0) * H + b] = lsA;
    cs[(2 * bx + 1) * H + b] = lsB;
}

// ================= KC: grid 257 x 384 threads =================
// Per block: redundant suffix-scan of cs -> co; conv xp rows inline; w/g/z for its
// 8-t chunk; atomic accumulate; ticket -> last block computes the output.
__global__ __launch_bounds__(384) void KC(
    const float* __restrict__ x, const float* __restrict__ cw, const float* __restrict__ cb,
    const float* __restrict__ ai, const float* __restrict__ lf, const float* __restrict__ zk,
    const float* __restrict__ cs, const float* __restrict__ qv, const float* __restrict__ ov,
    const float* __restrict__ Wv, const float* __restrict__ bv,
    float* __restrict__ zf, float* __restrict__ out) {
    __shared__ float zred[6][256];
    __shared__ float gred[6];
    __shared__ float zl[257];
    __shared__ int flag;
    int tid = threadIdx.x;
    int w = tid >> 6, lane = tid & 63;
    int c = blockIdx.x, ts = c * 8;

    // suffix sum of cs rows c+1..257 for this b-column
    float co0 = 0.f;
    #pragma unroll 8
    for (int cc = c + 1; cc < NCS; ++cc) co0 += cs[cc * H + tid];
    float qb = qv[tid];

    // conv xp rows ts..ts+7 at cols lane*4..+3
    float4 xv[8];
    {
        float w4[4] = {cw[0], cw[1], cw[2], cw[3]};
        float bb = cb[0];
        #pragma unroll
        for (int u = 0; u < 8; ++u) {
            float4 a = {0.f, 0.f, 0.f, 0.f};
            int t = ts + u;
            if (t < TP) {
                a.x = bb; a.y = bb; a.z = bb; a.w = bb;
                #pragma unroll
                for (int j = 0; j < 4; ++j) {
                    int tt = t - 3 + j;
                    if (tt >= 0 && tt < T_IN) {
                        float4 xr = *(const float4*)&x[tt * 256 + lane * 4];
                        float wj = w4[j];
                        a.x = fmaf(wj, xr.x, a.x);
                        a.y = fmaf(wj, xr.y, a.y);
                        a.z = fmaf(wj, xr.z, a.z);
                        a.w = fmaf(wj, xr.w, a.w);
                    }
                }
            }
            xv[u] = a;
        }
    }
    // prefetch chunk data
    float aiv[8], lfv[8], zkv[8];
    #pragma unroll
    for (int u = 0; u < 8; ++u) {
        if (ts + u < TP) {
            int idx = (ts + u) * H + tid;
            aiv[u] = ai[idx]; lfv[u] = lf[idx]; zkv[u] = zk[idx];
        } else {
            aiv[u] = -1e30f; lfv[u] = 0.f; zkv[u] = 0.f;
        }
    }
    // w -> per-wave g -> z/g partials (register suffix-sum, no barriers)
    float S = 0.f, gsum = 0.f;
    float z0 = 0.f, z1 = 0.f, z2 = 0.f, z3 = 0.f;
    #pragma unroll
    for (int u = 7; u >= 0; --u) {
        float wv = __expf(aiv[u] + co0 + S) * zkv[u] * qb;
        S += lfv[u];
        float s = wv;
        s += __shfl_xor(s, 1, 64);
        s += __shfl_xor(s, 2, 64);
        s += __shfl_xor(s, 4, 64);
        s += __shfl_xor(s, 8, 64);
        s += __shfl_xor(s, 16, 64);
        s += __shfl_xor(s, 32, 64);
        gsum += s;
        z0 = fmaf(s, xv[u].x, z0);
        z1 = fmaf(s, xv[u].y, z1);
        z2 = fmaf(s, xv[u].z, z2);
        z3 = fmaf(s, xv[u].w, z3);
    }
    zred[w][lane * 4 + 0] = z0;
    zred[w][lane * 4 + 1] = z1;
    zred[w][lane * 4 + 2] = z2;
    zred[w][lane * 4 + 3] = z3;
    if (lane == 0) gred[w] = gsum;
    __syncthreads();
    if (tid < 256) {
        float s = zred[0][tid] + zred[1][tid] + zred[2][tid]
                + zred[3][tid] + zred[4][tid] + zred[5][tid];
        atomicAdd(&zf[tid], s);
    }
    if (tid == 0)
        atomicAdd(&zf[256], gred[0] + gred[1] + gred[2] + gred[3] + gred[4] + gred[5]);
    __syncthreads();   // drains this block's atomics (vmcnt(0) before s_barrier)
    if (tid == 0) {
        __threadfence();
        int old = atomicAdd((int*)(zf + 257), 1);
        flag = (old == NC3 - 1) ? 1 : 0;
    }
    __syncthreads();
    if (!flag) return;

    // ---- last block: finalize out[384]
    if (tid < 257)
        zl[tid] = __hip_atomic_load(&zf[tid], __ATOMIC_RELAXED, __HIP_MEMORY_SCOPE_AGENT);
    __syncthreads();
    float G = zl[256];
    float den = fmaxf(fabsf(G), 1.0f);
    for (int r = 0; r < 64; ++r) {
        int row = w * 64 + r;
        float4 wv4 = *(const float4*)&Wv[row * 256 + lane * 4];
        float4 z4 = *(const float4*)&zl[lane * 4];
        float acc = fmaf(z4.x, wv4.x, fmaf(z4.y, wv4.y, fmaf(z4.z, wv4.z, z4.w * wv4.w)));
        #pragma unroll
        for (int off = 32; off; off >>= 1) acc += __shfl_down(acc, off, 64);
        if (lane == 0)
            out[row] = ov[row] * (acc + bv[row] * G) / den;
    }
}

extern "C" void kernel_launch(void* const* d_in, const int* in_sizes, int n_in,
                              void* d_out, int out_size, void* d_ws, size_t ws_size,
                              hipStream_t stream) {
    const float* x  = (const float*)d_in[0];
    const float* Wq = (const float*)d_in[1];  const float* bq = (const float*)d_in[2];
    const float* Wk = (const float*)d_in[3];  const float* bk = (const float*)d_in[4];
    const float* Wv = (const float*)d_in[5];  const float* bv = (const float*)d_in[6];
    const float* Wi = (const float*)d_in[7];  const float* bi = (const float*)d_in[8];
    const float* Wf = (const float*)d_in[9];  const float* bf = (const float*)d_in[10];
    const float* Wo = (const float*)d_in[11]; const float* bo = (const float*)d_in[12];
    const float* cw = (const float*)d_in[13]; const float* cb = (const float*)d_in[14];
    float* out = (float*)d_out;

    float* ws = (float*)d_ws;
    float* xpc = ws;                        // 129*4096 = 528384
    float* zk  = xpc + NTB * 4096;          // TP*H = 787584
    float* ai  = zk  + TP * H;              // TP*H
    float* lf  = ai  + TP * H;              // TP*H
    float* cs  = lf  + TP * H;              // NCS*H = 99072
    float* qv  = cs  + NCS * H;             // H
    float* ov  = qv  + H;                   // H
    float* zf  = ov  + H;                   // 280: z[256], G, ticket, pad

    KB<<<dim3(NTB, 7), 64, 0, stream>>>(x, cw, cb, Wk, bk, Wi, bi, Wf, bf,
                                        Wq, bq, Wo, bo, xpc, zk, ai, lf, cs, qv, ov, zf);
    KC<<<NC3, 384, 0, stream>>>(x, cw, cb, ai, lf, zk, cs, qv, ov, Wv, bv, zf, out);
}